// Round 1
// baseline (789.447 us; speedup 1.0000x reference)
//
#include <hip/hip_runtime.h>
#include <cmath>
#include <cstdint>
#include <cstddef>

typedef unsigned long long u64;
typedef unsigned int u32;

#define NPX   2500
#define NANCH 22500
#define PRE_TOPK 10000
#define NWORDS 160      // 160*64 = 10240 bits per NMS row

struct AnchorBase { float b[36]; };

// ---------------------------------------------------------------------------
// K1: 3x3 conv (512->512, pad 1) + bias + ReLU.
// One wave per (output row y, group of 8 output channels). Lanes 0..49 = x.
// Halo columns via shfl; weights are wave-uniform -> scalar loads.
// ---------------------------------------------------------------------------
__global__ __launch_bounds__(256) void k1_conv3(const float* __restrict__ feat,
                                                const float* __restrict__ wr,
                                                const float* __restrict__ br,
                                                float* __restrict__ rpn)
{
    int wid  = (blockIdx.x * 256 + threadIdx.x) >> 6;   // 0..3199
    int lane = threadIdx.x & 63;
    int y  = __builtin_amdgcn_readfirstlane(wid % 50);
    int og = __builtin_amdgcn_readfirstlane(wid / 50);  // 0..63
    int obase = og * 8;
    bool act = lane < 50;

    float acc[8];
#pragma unroll
    for (int oo = 0; oo < 8; ++oo) acc[oo] = 0.f;

    for (int c = 0; c < 512; ++c) {
        const float* fc = feat + c * NPX + y * 50;
        float t  = (act && y > 0)  ? fc[lane - 50] : 0.f;
        float m  =  act            ? fc[lane]      : 0.f;
        float bo = (act && y < 49) ? fc[lane + 50] : 0.f;
        float tl = __shfl_up(t, 1, 64);  tl = (lane == 0) ? 0.f : tl;
        float ml = __shfl_up(m, 1, 64);  ml = (lane == 0) ? 0.f : ml;
        float bl = __shfl_up(bo, 1, 64); bl = (lane == 0) ? 0.f : bl;
        float tr = __shfl_down(t, 1, 64);   // lane 49 pulls lane 50 == 0 -> right pad OK
        float mr = __shfl_down(m, 1, 64);
        float brr= __shfl_down(bo, 1, 64);
#pragma unroll
        for (int oo = 0; oo < 8; ++oo) {
            const float* wp = wr + ((size_t)(obase + oo) * 512 + c) * 9;
            float w0 = wp[0], w1 = wp[1], w2 = wp[2],
                  w3 = wp[3], w4 = wp[4], w5 = wp[5],
                  w6 = wp[6], w7 = wp[7], w8 = wp[8];
            float a = acc[oo];
            a = fmaf(w0, tl, a); a = fmaf(w1, t,  a); a = fmaf(w2, tr, a);
            a = fmaf(w3, ml, a); a = fmaf(w4, m,  a); a = fmaf(w5, mr, a);
            a = fmaf(w6, bl, a); a = fmaf(w7, bo, a); a = fmaf(w8, brr, a);
            acc[oo] = a;
        }
    }
    if (act) {
#pragma unroll
        for (int oo = 0; oo < 8; ++oo) {
            float v = acc[oo] + br[obase + oo];
            v = v > 0.f ? v : 0.f;
            rpn[(size_t)(obase + oo) * NPX + y * 50 + lane] = v;
        }
    }
}

// ---------------------------------------------------------------------------
// K2a: 1x1 heads partial GEMM. 45 outputs (9 cls + 36 reg) x 512 c, split in
// 8 deterministic c-chunks. Block = 64 px * 4 out-groups of 12.
// ---------------------------------------------------------------------------
__global__ __launch_bounds__(256) void k2a_heads(const float* __restrict__ rpn,
                                                 const float* __restrict__ wcls,
                                                 const float* __restrict__ wreg,
                                                 float* __restrict__ part)
{
    __shared__ float Wl[45 * 64];  // [u][c]
    int t  = threadIdx.x;
    int pb = blockIdx.x;           // 0..39
    int s  = blockIdx.y;           // 0..7
    int cb = s * 64;
    for (int e = t; e < 45 * 64; e += 256) {
        int u = e >> 6, c = e & 63;
        Wl[e] = (u < 9) ? wcls[u * 512 + cb + c] : wreg[(u - 9) * 512 + cb + c];
    }
    __syncthreads();
    int pxl = t & 63;
    int ug  = t >> 6;              // wave-uniform
    int px  = pb * 64 + pxl;
    int ubase = ug * 12;
    int ulim  = (ubase + 12 <= 45) ? 12 : (45 - ubase);
    float acc[12];
#pragma unroll
    for (int j = 0; j < 12; ++j) acc[j] = 0.f;
    bool ok = px < NPX;
    for (int c = 0; c < 64; ++c) {
        float v = ok ? rpn[(size_t)(cb + c) * NPX + px] : 0.f;
#pragma unroll
        for (int j = 0; j < 12; ++j)
            if (j < ulim) acc[j] = fmaf(v, Wl[(ubase + j) * 64 + c], acc[j]);
    }
    if (ok) {
        for (int j = 0; j < ulim; ++j)
            part[((size_t)s * 45 + ubase + j) * NPX + px] = acc[j];
    }
}

// ---------------------------------------------------------------------------
// K2b: reduce partials + bias, sigmoid, decode boxes, clip, validity, sort key.
// ---------------------------------------------------------------------------
__global__ __launch_bounds__(256) void k2b_decode(const float* __restrict__ part,
                                                  const float* __restrict__ bcls,
                                                  const float* __restrict__ breg,
                                                  AnchorBase ab,
                                                  float* __restrict__ score,
                                                  float* __restrict__ bx1, float* __restrict__ by1,
                                                  float* __restrict__ bx2, float* __restrict__ by2,
                                                  u32* __restrict__ valid,
                                                  u64* __restrict__ key)
{
    int id = blockIdx.x * 256 + threadIdx.x;
    if (id >= NANCH) return;
    int k  = id / NPX;
    int px = id - k * NPX;

    float z  = bcls[k];
    float d0 = breg[k * 4 + 0], d1 = breg[k * 4 + 1];
    float d2 = breg[k * 4 + 2], d3 = breg[k * 4 + 3];
#pragma unroll
    for (int s = 0; s < 8; ++s) {
        const float* p = part + (size_t)s * 45 * NPX;
        z  += p[(size_t)k * NPX + px];
        d0 += p[(size_t)(9 + k * 4 + 0) * NPX + px];
        d1 += p[(size_t)(9 + k * 4 + 1) * NPX + px];
        d2 += p[(size_t)(9 + k * 4 + 2) * NPX + px];
        d3 += p[(size_t)(9 + k * 4 + 3) * NPX + px];
    }
    float sc = 1.f / (1.f + expf(-z));

    int yy = px / 50, xx = px - (px / 50) * 50;
    float fx = (float)xx, fy = (float)yy;
    float ax1 = fx + ab.b[k * 4 + 0], ay1 = fy + ab.b[k * 4 + 1];
    float ax2 = fx + ab.b[k * 4 + 2], ay2 = fy + ab.b[k * 4 + 3];
    float aw = ax2 - ax1, ah = ay2 - ay1;
    float cx = ax1 + 0.5f * aw, cy = ay1 + 0.5f * ah;
    float pcx = d0 * aw + cx, pcy = d1 * ah + cy;
    float pw = expf(d2) * aw, ph = expf(d3) * ah;
    float x1 = pcx - 0.5f * pw, y1 = pcy - 0.5f * ph;
    float x2 = pcx + 0.5f * pw, y2 = pcy + 0.5f * ph;
    x1 = fminf(fmaxf(x1, 0.f), 800.f);
    y1 = fminf(fmaxf(y1, 0.f), 800.f);
    x2 = fminf(fmaxf(x2, 0.f), 800.f);
    y2 = fminf(fmaxf(y2, 0.f), 800.f);
    u32 v = ((x2 - x1) >= 16.f) && ((y2 - y1) >= 16.f);

    int f = px * 9 + k;            // reference flat anchor index
    score[f] = sc;
    bx1[f] = x1; by1[f] = y1; bx2[f] = x2; by2[f] = y2;
    valid[f] = v;
    u32 sb = __float_as_uint(sc);  // positive float: bits monotone
    key[f] = ((u64)(~sb) << 32) | (u32)f;   // ascending key == desc score, asc idx
}

// ---------------------------------------------------------------------------
// K3a: exact ranking by counting (stable top-k). rank[i] = #{key_j < key_i}.
// ---------------------------------------------------------------------------
__global__ __launch_bounds__(256) void k3a_rank(const u64* __restrict__ key,
                                                u32* __restrict__ rank)
{
    __shared__ u64 sk[4500];
    int t  = threadIdx.x;
    int jb = blockIdx.y;           // 0..4
    for (int e = t; e < 4500; e += 256) sk[e] = key[jb * 4500 + e];
    __syncthreads();
    int i = blockIdx.x * 256 + t;
    if (i >= NANCH) return;
    u64 ki = key[i];
    u32 cnt = 0;
#pragma unroll 8
    for (int j = 0; j < 4500; ++j) cnt += (sk[j] < ki) ? 1u : 0u;
    atomicAdd(&rank[i], cnt);
}

// ---------------------------------------------------------------------------
// K3b: scatter top-10000 into sorted arrays; invalid -> initial removed bit.
// ---------------------------------------------------------------------------
__global__ __launch_bounds__(256) void k3b_gather(const u32* __restrict__ rank,
                                                  const float* __restrict__ score,
                                                  const float* __restrict__ bx1, const float* __restrict__ by1,
                                                  const float* __restrict__ bx2, const float* __restrict__ by2,
                                                  const u32* __restrict__ valid,
                                                  float* __restrict__ sS,
                                                  float* __restrict__ sx1, float* __restrict__ sy1,
                                                  float* __restrict__ sx2, float* __restrict__ sy2,
                                                  float* __restrict__ sA,
                                                  u64* __restrict__ rinit)
{
    int i = blockIdx.x * 256 + threadIdx.x;
    if (i >= NANCH) return;
    u32 r = rank[i];
    if (r >= PRE_TOPK) return;
    float x1 = bx1[i], y1 = by1[i], x2 = bx2[i], y2 = by2[i];
    sS[r] = score[i];
    sx1[r] = x1; sy1[r] = y1; sx2[r] = x2; sy2[r] = y2;
    sA[r] = (x2 - x1) * (y2 - y1);
    if (!valid[i]) atomicOr(&rinit[r >> 6], 1ull << (r & 63));
}

// ---------------------------------------------------------------------------
// K4: pairwise suppression matrix. rows[i] bit j set iff j>i and IoU>0.7.
// inter > 0.7*union  <=>  inter/union > 0.7 (union>=0; 0/0 -> false, matches NaN).
// ---------------------------------------------------------------------------
__global__ __launch_bounds__(256) void k4_mat(const float* __restrict__ sx1, const float* __restrict__ sy1,
                                              const float* __restrict__ sx2, const float* __restrict__ sy2,
                                              const float* __restrict__ sA,
                                              u64* __restrict__ rows)
{
    __shared__ float jx1[1024], jy1[1024], jx2[1024], jy2[1024], ja[1024];
    int t  = threadIdx.x;
    int ib = blockIdx.x;           // 0..39
    int jc = blockIdx.y;           // 0..9
    for (int e = t; e < 1024; e += 256) {
        int j = jc * 1024 + e;
        bool okj = j < PRE_TOPK;
        jx1[e] = okj ? sx1[j] : 0.f;
        jy1[e] = okj ? sy1[j] : 0.f;
        jx2[e] = okj ? sx2[j] : 0.f;
        jy2[e] = okj ? sy2[j] : 0.f;
        ja[e]  = okj ? sA[j]  : 0.f;
    }
    __syncthreads();
    int i = ib * 256 + t;
    if (i >= PRE_TOPK) return;
    u64* rowp = rows + (size_t)i * NWORDS + jc * 16;
    if (jc * 1024 + 1023 <= i) {   // whole chunk has j <= i -> zeros
#pragma unroll
        for (int w = 0; w < 16; ++w) rowp[w] = 0ull;
        return;
    }
    float x1 = sx1[i], y1 = sy1[i], x2 = sx2[i], y2 = sy2[i], ai = sA[i];
    u64 word = 0;
#pragma unroll 4
    for (int e = 0; e < 1024; ++e) {
        int j = jc * 1024 + e;
        float xx1 = fmaxf(x1, jx1[e]);
        float yy1 = fmaxf(y1, jy1[e]);
        float xx2 = fminf(x2, jx2[e]);
        float yy2 = fminf(y2, jy2[e]);
        float iw = fmaxf(xx2 - xx1, 0.f);
        float ih = fmaxf(yy2 - yy1, 0.f);
        float inter = iw * ih;
        float uni = ai + ja[e] - inter;
        bool sup = (inter > 0.7f * uni) && (j > i) && (j < PRE_TOPK);
        word |= ((u64)sup) << (e & 63);
        if ((e & 63) == 63) { rowp[e >> 6] = word; word = 0; }
    }
}

// ---------------------------------------------------------------------------
// K5: single-wave greedy scan over the suppression matrix + compaction.
// Removed bitmap distributed: lane l owns words {l, l+64, l+128}. Serial cost
// scales with #kept (skip-to-next-zero-bit). Early exit at 2000 kept.
// Output = kept boxes in score order, rest zero (out pre-zeroed).
// ---------------------------------------------------------------------------
__global__ __launch_bounds__(64) void k5_scan(const u64* __restrict__ rows,
                                              const u64* __restrict__ rinit,
                                              const float* __restrict__ sS,
                                              const float* __restrict__ sx1, const float* __restrict__ sy1,
                                              const float* __restrict__ sx2, const float* __restrict__ sy2,
                                              float* __restrict__ out)
{
    __shared__ int keptList[2000];
    __shared__ int kcnt;
    int l = threadIdx.x;
    u64 r0 = rinit[l];
    u64 r1 = rinit[64 + l];
    u64 r2 = (l < 32) ? rinit[128 + l] : ~0ull;
    int cnt = 0;
    bool done = false;
    for (int w = 0; w < 157 && !done; ++w) {
        int slot = w >> 6, owner = w & 63;
        u64 val = (slot == 0) ? r0 : (slot == 1) ? r1 : r2;
        u64 rw = __shfl(val, owner, 64);
        u64 wmask = (w == 156) ? 0xFFFFull : ~0ull;   // i < 10000
        u64 avail = (~rw) & wmask;
        while (avail) {
            int b = __ffsll((unsigned long long)avail) - 1;
            int i = (w << 6) + b;
            const u64* row = rows + (size_t)i * NWORDS;
            u64 q0 = row[l];
            u64 q1 = row[64 + l];
            u64 q2 = (l < 32) ? row[128 + l] : 0ull;
            u64 rww = row[w];
            r0 |= q0; r1 |= q1; r2 |= q2;
            rw |= rww;
            if (l == 0) keptList[cnt] = i;
            cnt++;
            if (cnt >= 2000) { done = true; break; }
            u64 hi = (b == 63) ? 0ull : (~0ull << (b + 1));
            avail = (~rw) & hi & wmask;
        }
    }
    if (l == 0) kcnt = cnt;
    __syncthreads();
    int K = kcnt;
    for (int r = l; r < K; r += 64) {
        int j = keptList[r];
        out[r * 4 + 0] = sx1[j];
        out[r * 4 + 1] = sy1[j];
        out[r * 4 + 2] = sx2[j];
        out[r * 4 + 3] = sy2[j];
        out[8000 + r]  = sS[j];
    }
}

// ---------------------------------------------------------------------------
extern "C" void kernel_launch(void* const* d_in, const int* in_sizes, int n_in,
                              void* d_out, int out_size, void* d_ws, size_t ws_size,
                              hipStream_t stream)
{
    (void)in_sizes; (void)n_in; (void)out_size; (void)ws_size;
    const float* feat = (const float*)d_in[1];
    const float* wrpn = (const float*)d_in[3];
    const float* brpn = (const float*)d_in[4];
    const float* wcls = (const float*)d_in[5];
    const float* bcls = (const float*)d_in[6];
    const float* wreg = (const float*)d_in[7];
    const float* breg = (const float*)d_in[8];
    float* out = (float*)d_out;

    char* ws = (char*)d_ws;
    float* rpn   = (float*)(ws + 0);          // 512*2500 f32          = 5,120,000
    float* part  = (float*)(ws + 5120000);    // 8*45*2500 f32         = 3,600,000
    float* score = (float*)(ws + 8720000);    // 22500 f32
    float* bx1   = (float*)(ws + 8810000);
    float* by1   = (float*)(ws + 8900000);
    float* bx2   = (float*)(ws + 8990000);
    float* by2   = (float*)(ws + 9080000);
    u32*   valid = (u32*)  (ws + 9170000);
    u64*   key   = (u64*)  (ws + 9260000);    // 22500 u64
    u32*   rank  = (u32*)  (ws + 9440000);
    float* sS    = (float*)(ws + 9530000);    // 10000 f32
    float* sx1   = (float*)(ws + 9570000);
    float* sy1   = (float*)(ws + 9610000);
    float* sx2   = (float*)(ws + 9650000);
    float* sy2   = (float*)(ws + 9690000);
    float* sA    = (float*)(ws + 9730000);
    u64*   rinit = (u64*)  (ws + 9770000);    // 160 u64
    u64*   rows  = (u64*)  (ws + 9771280);    // 10000*160 u64 = 12,800,000
    // total ws use: 22,571,280 bytes

    // Base anchors host-side, fp32 ops mirroring jnp (round half-to-even).
    AnchorBase ab;
    {
        const float scales[3] = {128.f, 256.f, 512.f};
        const float aspect[3] = {0.5f, 1.f, 2.f};
        for (int ai = 0; ai < 3; ++ai) {
            float hr = sqrtf(aspect[ai]);
            float wratio = 1.0f / hr;
            for (int si = 0; si < 3; ++si) {
                float wsz = wratio * scales[si];
                float hsz = hr * scales[si];
                int a = ai * 3 + si;
                ab.b[a * 4 + 0] = rintf(-wsz / 2.0f);
                ab.b[a * 4 + 1] = rintf(-hsz / 2.0f);
                ab.b[a * 4 + 2] = rintf( wsz / 2.0f);
                ab.b[a * 4 + 3] = rintf( hsz / 2.0f);
            }
        }
    }

    hipMemsetAsync(rank, 0, NANCH * sizeof(u32), stream);
    hipMemsetAsync(rinit, 0, NWORDS * sizeof(u64), stream);
    hipMemsetAsync(out, 0, 10000 * sizeof(float), stream);

    k1_conv3 <<<800, 256, 0, stream>>>(feat, wrpn, brpn, rpn);
    k2a_heads<<<dim3(40, 8), 256, 0, stream>>>(rpn, wcls, wreg, part);
    k2b_decode<<<88, 256, 0, stream>>>(part, bcls, breg, ab, score, bx1, by1, bx2, by2, valid, key);
    k3a_rank <<<dim3(88, 5), 256, 0, stream>>>(key, rank);
    k3b_gather<<<88, 256, 0, stream>>>(rank, score, bx1, by1, bx2, by2, valid,
                                       sS, sx1, sy1, sx2, sy2, sA, rinit);
    k4_mat   <<<dim3(40, 10), 256, 0, stream>>>(sx1, sy1, sx2, sy2, sA, rows);
    k5_scan  <<<1, 64, 0, stream>>>(rows, rinit, sS, sx1, sy1, sx2, sy2, out);
}

// Round 2
// 573.722 us; speedup vs baseline: 1.3760x; 1.3760x over previous
//
#include <hip/hip_runtime.h>
#include <cmath>
#include <cstdint>
#include <cstddef>

typedef unsigned long long u64;
typedef unsigned int u32;

#define NPX   2500
#define NANCH 22500
#define PRE_TOPK 10000
#define NWORDS 160      // 160*64 = 10240 bits per NMS row

struct AnchorBase { float b[36]; };

// ---------------------------------------------------------------------------
// KT: transpose weights [oc][c][9] -> [c][oc][9] so one (c, og) needs 72
// contiguous dwords (scalar-load friendly).
// ---------------------------------------------------------------------------
__global__ __launch_bounds__(256) void kt_w(const float* __restrict__ wr,
                                            float* __restrict__ wt)
{
    int e = blockIdx.x * 256 + threadIdx.x;   // over 512*512*9 = 2359296
    if (e >= 512 * 512 * 9) return;
    int tap = e % 9;
    int rest = e / 9;
    int oc = rest & 511;
    int c  = rest >> 9;
    wt[e] = wr[((size_t)oc * 512 + c) * 9 + tap];
}

// ---------------------------------------------------------------------------
// K1 v2: 3x3 conv partials. Wave = 8 oc x 2 rows x 128-c chunk.
// 6400 waves (78% occupancy). 144 FMA per 72 weight dwords per c-iter.
// Weights via contiguous scalar loads (two halves of 36 to fit SGPRs).
// ---------------------------------------------------------------------------
__global__ __launch_bounds__(256) void k1_conv3(const float* __restrict__ feat,
                                                const float* __restrict__ wt,
                                                float* __restrict__ pk1)
{
    int wid  = (blockIdx.x * 256 + threadIdx.x) >> 6;   // 0..6399
    int lane = threadIdx.x & 63;
    int cc = __builtin_amdgcn_readfirstlane(wid / 1600);       // c-chunk 0..3
    int r  = wid - cc * 1600;
    int og = __builtin_amdgcn_readfirstlane(r / 25);           // 0..63
    int yp = __builtin_amdgcn_readfirstlane(r - og * 25);      // 0..24
    int ry = yp * 2;                                           // rows ry, ry+1
    int obase = og * 8;
    bool act = lane < 50;

    float acc[16];
#pragma unroll
    for (int i = 0; i < 16; ++i) acc[i] = 0.f;

    int c0 = cc * 128;
    for (int ci = 0; ci < 128; ++ci) {
        int c = c0 + ci;
        const float* fb = feat + (size_t)c * NPX + ry * 50 + lane;
        // feat rows ry-1 .. ry+2 (ry+1 <= 49 always; ry+2 invalid iff ry==48)
        float f0 = (act && ry > 0)  ? fb[-50] : 0.f;
        float f1 =  act             ? fb[0]   : 0.f;
        float f2 =  act             ? fb[50]  : 0.f;
        float f3 = (act && ry < 48) ? fb[100] : 0.f;
        float l0 = __shfl_up(f0, 1, 64);  l0 = (lane == 0) ? 0.f : l0;
        float l1 = __shfl_up(f1, 1, 64);  l1 = (lane == 0) ? 0.f : l1;
        float l2 = __shfl_up(f2, 1, 64);  l2 = (lane == 0) ? 0.f : l2;
        float l3 = __shfl_up(f3, 1, 64);  l3 = (lane == 0) ? 0.f : l3;
        float r0 = __shfl_down(f0, 1, 64);   // lane 49 pulls lane 50 == 0
        float r1 = __shfl_down(f1, 1, 64);
        float r2 = __shfl_down(f2, 1, 64);
        float r3 = __shfl_down(f3, 1, 64);

#pragma unroll
        for (int half = 0; half < 2; ++half) {
            const float* wp = wt + ((size_t)c * 512 + obase) * 9 + half * 36;
            float w[36];
#pragma unroll
            for (int i = 0; i < 36; ++i) w[i] = wp[i];
#pragma unroll
            for (int oo = 0; oo < 4; ++oo) {
                int o = half * 4 + oo;
                const float* W = &w[oo * 9];
                float a0 = acc[o * 2], a1 = acc[o * 2 + 1];
                a0 = fmaf(W[0], l0, a0); a0 = fmaf(W[1], f0, a0); a0 = fmaf(W[2], r0, a0);
                a0 = fmaf(W[3], l1, a0); a0 = fmaf(W[4], f1, a0); a0 = fmaf(W[5], r1, a0);
                a0 = fmaf(W[6], l2, a0); a0 = fmaf(W[7], f2, a0); a0 = fmaf(W[8], r2, a0);
                a1 = fmaf(W[0], l1, a1); a1 = fmaf(W[1], f1, a1); a1 = fmaf(W[2], r1, a1);
                a1 = fmaf(W[3], l2, a1); a1 = fmaf(W[4], f2, a1); a1 = fmaf(W[5], r2, a1);
                a1 = fmaf(W[6], l3, a1); a1 = fmaf(W[7], f3, a1); a1 = fmaf(W[8], r3, a1);
                acc[o * 2] = a0; acc[o * 2 + 1] = a1;
            }
        }
    }
    if (act) {
#pragma unroll
        for (int oo = 0; oo < 8; ++oo) {
#pragma unroll
            for (int rr = 0; rr < 2; ++rr) {
                pk1[((size_t)cc * 512 + obase + oo) * NPX + (ry + rr) * 50 + lane]
                    = acc[oo * 2 + rr];
            }
        }
    }
}

// ---------------------------------------------------------------------------
// K1r: reduce 4 c-chunk partials + bias + ReLU -> rpn.
// ---------------------------------------------------------------------------
__global__ __launch_bounds__(256) void k1r(const float* __restrict__ pk1,
                                           const float* __restrict__ br,
                                           float* __restrict__ rpn)
{
    int e = blockIdx.x * 256 + threadIdx.x;   // 512*2500 = 1,280,000
    if (e >= 512 * NPX) return;
    int oc = e / NPX;
    float v = pk1[e] + pk1[512 * NPX + e] + pk1[2 * 512 * NPX + e]
            + pk1[3 * 512 * NPX + e] + br[oc];
    rpn[e] = v > 0.f ? v : 0.f;
}

// ---------------------------------------------------------------------------
// K2a: 1x1 heads partial GEMM. 45 outputs (9 cls + 36 reg) x 512 c, split in
// 8 deterministic c-chunks. Block = 64 px * 4 out-groups of 12.
// ---------------------------------------------------------------------------
__global__ __launch_bounds__(256) void k2a_heads(const float* __restrict__ rpn,
                                                 const float* __restrict__ wcls,
                                                 const float* __restrict__ wreg,
                                                 float* __restrict__ part)
{
    __shared__ float Wl[45 * 64];  // [u][c]
    int t  = threadIdx.x;
    int pb = blockIdx.x;           // 0..39
    int s  = blockIdx.y;           // 0..7
    int cb = s * 64;
    for (int e = t; e < 45 * 64; e += 256) {
        int u = e >> 6, c = e & 63;
        Wl[e] = (u < 9) ? wcls[u * 512 + cb + c] : wreg[(u - 9) * 512 + cb + c];
    }
    __syncthreads();
    int pxl = t & 63;
    int ug  = t >> 6;              // wave-uniform
    int px  = pb * 64 + pxl;
    int ubase = ug * 12;
    int ulim  = (ubase + 12 <= 45) ? 12 : (45 - ubase);
    float acc[12];
#pragma unroll
    for (int j = 0; j < 12; ++j) acc[j] = 0.f;
    bool ok = px < NPX;
    for (int c = 0; c < 64; ++c) {
        float v = ok ? rpn[(size_t)(cb + c) * NPX + px] : 0.f;
#pragma unroll
        for (int j = 0; j < 12; ++j)
            if (j < ulim) acc[j] = fmaf(v, Wl[(ubase + j) * 64 + c], acc[j]);
    }
    if (ok) {
        for (int j = 0; j < ulim; ++j)
            part[((size_t)s * 45 + ubase + j) * NPX + px] = acc[j];
    }
}

// ---------------------------------------------------------------------------
// K2b: reduce partials + bias, sigmoid, decode boxes, clip, validity, sort key.
// ---------------------------------------------------------------------------
__global__ __launch_bounds__(256) void k2b_decode(const float* __restrict__ part,
                                                  const float* __restrict__ bcls,
                                                  const float* __restrict__ breg,
                                                  AnchorBase ab,
                                                  float* __restrict__ score,
                                                  float* __restrict__ bx1, float* __restrict__ by1,
                                                  float* __restrict__ bx2, float* __restrict__ by2,
                                                  u32* __restrict__ valid,
                                                  u64* __restrict__ key)
{
    int id = blockIdx.x * 256 + threadIdx.x;
    if (id >= NANCH) return;
    int k  = id / NPX;
    int px = id - k * NPX;

    float z  = bcls[k];
    float d0 = breg[k * 4 + 0], d1 = breg[k * 4 + 1];
    float d2 = breg[k * 4 + 2], d3 = breg[k * 4 + 3];
#pragma unroll
    for (int s = 0; s < 8; ++s) {
        const float* p = part + (size_t)s * 45 * NPX;
        z  += p[(size_t)k * NPX + px];
        d0 += p[(size_t)(9 + k * 4 + 0) * NPX + px];
        d1 += p[(size_t)(9 + k * 4 + 1) * NPX + px];
        d2 += p[(size_t)(9 + k * 4 + 2) * NPX + px];
        d3 += p[(size_t)(9 + k * 4 + 3) * NPX + px];
    }
    float sc = 1.f / (1.f + expf(-z));

    int yy = px / 50, xx = px - (px / 50) * 50;
    float fx = (float)xx, fy = (float)yy;
    float ax1 = fx + ab.b[k * 4 + 0], ay1 = fy + ab.b[k * 4 + 1];
    float ax2 = fx + ab.b[k * 4 + 2], ay2 = fy + ab.b[k * 4 + 3];
    float aw = ax2 - ax1, ah = ay2 - ay1;
    float cx = ax1 + 0.5f * aw, cy = ay1 + 0.5f * ah;
    float pcx = d0 * aw + cx, pcy = d1 * ah + cy;
    float pw = expf(d2) * aw, ph = expf(d3) * ah;
    float x1 = pcx - 0.5f * pw, y1 = pcy - 0.5f * ph;
    float x2 = pcx + 0.5f * pw, y2 = pcy + 0.5f * ph;
    x1 = fminf(fmaxf(x1, 0.f), 800.f);
    y1 = fminf(fmaxf(y1, 0.f), 800.f);
    x2 = fminf(fmaxf(x2, 0.f), 800.f);
    y2 = fminf(fmaxf(y2, 0.f), 800.f);
    u32 v = ((x2 - x1) >= 16.f) && ((y2 - y1) >= 16.f);

    int f = px * 9 + k;            // reference flat anchor index
    score[f] = sc;
    bx1[f] = x1; by1[f] = y1; bx2[f] = x2; by2[f] = y2;
    valid[f] = v;
    u32 sb = __float_as_uint(sc);  // positive float: bits monotone
    key[f] = ((u64)(~sb) << 32) | (u32)f;   // ascending key == desc score, asc idx
}

// ---------------------------------------------------------------------------
// K3a: exact ranking by counting (stable top-k). rank[i] = #{key_j < key_i}.
// ---------------------------------------------------------------------------
__global__ __launch_bounds__(256) void k3a_rank(const u64* __restrict__ key,
                                                u32* __restrict__ rank)
{
    __shared__ u64 sk[4500];
    int t  = threadIdx.x;
    int jb = blockIdx.y;           // 0..4
    for (int e = t; e < 4500; e += 256) sk[e] = key[jb * 4500 + e];
    __syncthreads();
    int i = blockIdx.x * 256 + t;
    if (i >= NANCH) return;
    u64 ki = key[i];
    u32 cnt = 0;
#pragma unroll 8
    for (int j = 0; j < 4500; ++j) cnt += (sk[j] < ki) ? 1u : 0u;
    atomicAdd(&rank[i], cnt);
}

// ---------------------------------------------------------------------------
// K3b: scatter top-10000 into sorted arrays; invalid -> initial removed bit.
// ---------------------------------------------------------------------------
__global__ __launch_bounds__(256) void k3b_gather(const u32* __restrict__ rank,
                                                  const float* __restrict__ score,
                                                  const float* __restrict__ bx1, const float* __restrict__ by1,
                                                  const float* __restrict__ bx2, const float* __restrict__ by2,
                                                  const u32* __restrict__ valid,
                                                  float* __restrict__ sS,
                                                  float* __restrict__ sx1, float* __restrict__ sy1,
                                                  float* __restrict__ sx2, float* __restrict__ sy2,
                                                  float* __restrict__ sA,
                                                  u64* __restrict__ rinit)
{
    int i = blockIdx.x * 256 + threadIdx.x;
    if (i >= NANCH) return;
    u32 r = rank[i];
    if (r >= PRE_TOPK) return;
    float x1 = bx1[i], y1 = by1[i], x2 = bx2[i], y2 = by2[i];
    sS[r] = score[i];
    sx1[r] = x1; sy1[r] = y1; sx2[r] = x2; sy2[r] = y2;
    sA[r] = (x2 - x1) * (y2 - y1);
    if (!valid[i]) atomicOr(&rinit[r >> 6], 1ull << (r & 63));
}

// ---------------------------------------------------------------------------
// K4: pairwise suppression matrix. rows[i] bit j set iff j>i and IoU>0.7.
// ---------------------------------------------------------------------------
__global__ __launch_bounds__(256) void k4_mat(const float* __restrict__ sx1, const float* __restrict__ sy1,
                                              const float* __restrict__ sx2, const float* __restrict__ sy2,
                                              const float* __restrict__ sA,
                                              u64* __restrict__ rows)
{
    __shared__ float jx1[1024], jy1[1024], jx2[1024], jy2[1024], ja[1024];
    int t  = threadIdx.x;
    int ib = blockIdx.x;           // 0..39
    int jc = blockIdx.y;           // 0..9
    for (int e = t; e < 1024; e += 256) {
        int j = jc * 1024 + e;
        bool okj = j < PRE_TOPK;
        jx1[e] = okj ? sx1[j] : 0.f;
        jy1[e] = okj ? sy1[j] : 0.f;
        jx2[e] = okj ? sx2[j] : 0.f;
        jy2[e] = okj ? sy2[j] : 0.f;
        ja[e]  = okj ? sA[j]  : 0.f;
    }
    __syncthreads();
    int i = ib * 256 + t;
    if (i >= PRE_TOPK) return;
    u64* rowp = rows + (size_t)i * NWORDS + jc * 16;
    if (jc * 1024 + 1023 <= i) {   // whole chunk has j <= i -> zeros
#pragma unroll
        for (int w = 0; w < 16; ++w) rowp[w] = 0ull;
        return;
    }
    float x1 = sx1[i], y1 = sy1[i], x2 = sx2[i], y2 = sy2[i], ai = sA[i];
    u64 word = 0;
#pragma unroll 4
    for (int e = 0; e < 1024; ++e) {
        int j = jc * 1024 + e;
        float xx1 = fmaxf(x1, jx1[e]);
        float yy1 = fmaxf(y1, jy1[e]);
        float xx2 = fminf(x2, jx2[e]);
        float yy2 = fminf(y2, jy2[e]);
        float iw = fmaxf(xx2 - xx1, 0.f);
        float ih = fmaxf(yy2 - yy1, 0.f);
        float inter = iw * ih;
        float uni = ai + ja[e] - inter;
        bool sup = (inter > 0.7f * uni) && (j > i) && (j < PRE_TOPK);
        word |= ((u64)sup) << (e & 63);
        if ((e & 63) == 63) { rowp[e >> 6] = word; word = 0; }
    }
}

// ---------------------------------------------------------------------------
// K5: single-wave greedy scan over the suppression matrix + compaction.
// ---------------------------------------------------------------------------
__global__ __launch_bounds__(64) void k5_scan(const u64* __restrict__ rows,
                                              const u64* __restrict__ rinit,
                                              const float* __restrict__ sS,
                                              const float* __restrict__ sx1, const float* __restrict__ sy1,
                                              const float* __restrict__ sx2, const float* __restrict__ sy2,
                                              float* __restrict__ out)
{
    __shared__ int keptList[2000];
    __shared__ int kcnt;
    int l = threadIdx.x;
    u64 r0 = rinit[l];
    u64 r1 = rinit[64 + l];
    u64 r2 = (l < 32) ? rinit[128 + l] : ~0ull;
    int cnt = 0;
    bool done = false;
    for (int w = 0; w < 157 && !done; ++w) {
        int slot = w >> 6, owner = w & 63;
        u64 val = (slot == 0) ? r0 : (slot == 1) ? r1 : r2;
        u64 rw = __shfl(val, owner, 64);
        u64 wmask = (w == 156) ? 0xFFFFull : ~0ull;   // i < 10000
        u64 avail = (~rw) & wmask;
        while (avail) {
            int b = __ffsll((unsigned long long)avail) - 1;
            int i = (w << 6) + b;
            const u64* row = rows + (size_t)i * NWORDS;
            u64 q0 = row[l];
            u64 q1 = row[64 + l];
            u64 q2 = (l < 32) ? row[128 + l] : 0ull;
            u64 rww = row[w];
            r0 |= q0; r1 |= q1; r2 |= q2;
            rw |= rww;
            if (l == 0) keptList[cnt] = i;
            cnt++;
            if (cnt >= 2000) { done = true; break; }
            u64 hi = (b == 63) ? 0ull : (~0ull << (b + 1));
            avail = (~rw) & hi & wmask;
        }
    }
    if (l == 0) kcnt = cnt;
    __syncthreads();
    int K = kcnt;
    for (int r = l; r < K; r += 64) {
        int j = keptList[r];
        out[r * 4 + 0] = sx1[j];
        out[r * 4 + 1] = sy1[j];
        out[r * 4 + 2] = sx2[j];
        out[r * 4 + 3] = sy2[j];
        out[8000 + r]  = sS[j];
    }
}

// ---------------------------------------------------------------------------
extern "C" void kernel_launch(void* const* d_in, const int* in_sizes, int n_in,
                              void* d_out, int out_size, void* d_ws, size_t ws_size,
                              hipStream_t stream)
{
    (void)in_sizes; (void)n_in; (void)out_size; (void)ws_size;
    const float* feat = (const float*)d_in[1];
    const float* wrpn = (const float*)d_in[3];
    const float* brpn = (const float*)d_in[4];
    const float* wcls = (const float*)d_in[5];
    const float* bcls = (const float*)d_in[6];
    const float* wreg = (const float*)d_in[7];
    const float* breg = (const float*)d_in[8];
    float* out = (float*)d_out;

    char* ws = (char*)d_ws;
    // Live ranges allow aliasing: pk1 [k1..k1r) overlaps part/misc/rows which
    // are all written strictly after k1r (memsets deferred past k1r).
    float* rpn   = (float*)(ws + 0);          //  5,120,000
    float* pk1   = (float*)(ws + 5120000);    // 20,480,000 (dead after k1r)
    float* part  = (float*)(ws + 5120000);    //  3,600,000 (k2a+)
    float* score = (float*)(ws + 8720000);
    float* bx1   = (float*)(ws + 8810000);
    float* by1   = (float*)(ws + 8900000);
    float* bx2   = (float*)(ws + 8990000);
    float* by2   = (float*)(ws + 9080000);
    u32*   valid = (u32*)  (ws + 9170000);
    u64*   key   = (u64*)  (ws + 9260000);
    u32*   rank  = (u32*)  (ws + 9440000);
    float* sS    = (float*)(ws + 9530000);
    float* sx1   = (float*)(ws + 9570000);
    float* sy1   = (float*)(ws + 9610000);
    float* sx2   = (float*)(ws + 9650000);
    float* sy2   = (float*)(ws + 9690000);
    float* sA    = (float*)(ws + 9730000);
    u64*   rinit = (u64*)  (ws + 9770000);    // 1,280
    u64*   rows  = (u64*)  (ws + 9771280);    // 12,800,000 (k4+)
    float* wt    = (float*)(ws + 25600000);   //  9,437,184 (kt..k1)
    // total ws use: 35,037,184 bytes

    AnchorBase ab;
    {
        const float scales[3] = {128.f, 256.f, 512.f};
        const float aspect[3] = {0.5f, 1.f, 2.f};
        for (int ai = 0; ai < 3; ++ai) {
            float hr = sqrtf(aspect[ai]);
            float wratio = 1.0f / hr;
            for (int si = 0; si < 3; ++si) {
                float wsz = wratio * scales[si];
                float hsz = hr * scales[si];
                int a = ai * 3 + si;
                ab.b[a * 4 + 0] = rintf(-wsz / 2.0f);
                ab.b[a * 4 + 1] = rintf(-hsz / 2.0f);
                ab.b[a * 4 + 2] = rintf( wsz / 2.0f);
                ab.b[a * 4 + 3] = rintf( hsz / 2.0f);
            }
        }
    }

    kt_w     <<<9216, 256, 0, stream>>>(wrpn, wt);
    k1_conv3 <<<1600, 256, 0, stream>>>(feat, wt, pk1);
    k1r      <<<5000, 256, 0, stream>>>(pk1, brpn, rpn);

    // memsets AFTER k1r: rank/rinit/out regions alias nothing from here on,
    // and pk1 (which overlapped rank/rinit) is dead.
    hipMemsetAsync(rank, 0, NANCH * sizeof(u32), stream);
    hipMemsetAsync(rinit, 0, NWORDS * sizeof(u64), stream);
    hipMemsetAsync(out, 0, 10000 * sizeof(float), stream);

    k2a_heads<<<dim3(40, 8), 256, 0, stream>>>(rpn, wcls, wreg, part);
    k2b_decode<<<88, 256, 0, stream>>>(part, bcls, breg, ab, score, bx1, by1, bx2, by2, valid, key);
    k3a_rank <<<dim3(88, 5), 256, 0, stream>>>(key, rank);
    k3b_gather<<<88, 256, 0, stream>>>(rank, score, bx1, by1, bx2, by2, valid,
                                       sS, sx1, sy1, sx2, sy2, sA, rinit);
    k4_mat   <<<dim3(40, 10), 256, 0, stream>>>(sx1, sy1, sx2, sy2, sA, rows);
    k5_scan  <<<1, 64, 0, stream>>>(rows, rinit, sS, sx1, sy1, sx2, sy2, out);
}

// Round 3
// 543.145 us; speedup vs baseline: 1.4535x; 1.0563x over previous
//
#include <hip/hip_runtime.h>
#include <cmath>
#include <cstdint>
#include <cstddef>

typedef unsigned long long u64;
typedef unsigned int u32;

#define NPX   2500
#define NANCH 22500
#define PRE_TOPK 10000
#define NWORDS 160      // 160*64 = 10240 bits per NMS row

struct AnchorBase { float b[36]; };

typedef __attribute__((ext_vector_type(8))) short bf16x8;
typedef __attribute__((ext_vector_type(4))) float f32x4;

__device__ inline unsigned short f2bf(float f) {
    u32 u = __float_as_uint(f);
    u32 r = u + 0x7fffu + ((u >> 16) & 1u);
    return (unsigned short)(r >> 16);
}
__device__ inline float bf2f(unsigned short h) {
    return __uint_as_float(((u32)h) << 16);
}

// ---------------------------------------------------------------------------
// P1: feat [c][px] -> Xt[row][c] bf16 hi/lo, zero-padded 52x64 grid.
// row = (y+1)*64 + (x+1). LDS tile transpose for coalescing both sides.
// ---------------------------------------------------------------------------
__global__ __launch_bounds__(256) void p1_xt(const float* __restrict__ feat,
                                             unsigned short* __restrict__ xthi,
                                             unsigned short* __restrict__ xtlo)
{
    __shared__ float tile[64][65];
    int t = threadIdx.x;
    int pxb = blockIdx.x * 64;
    int cb  = blockIdx.y * 64;
    int tx = t & 63, ty = t >> 6;
#pragma unroll
    for (int i = 0; i < 16; ++i) {
        int cl = ty + i * 4;
        int px = pxb + tx;
        tile[cl][tx] = (px < NPX) ? feat[(size_t)(cb + cl) * NPX + px] : 0.f;
    }
    __syncthreads();
#pragma unroll
    for (int i = 0; i < 16; ++i) {
        int pl = ty + i * 4;
        int px = pxb + pl;
        if (px < NPX) {
            int y = px / 50, x = px - y * 50;
            int row = (y + 1) * 64 + x + 1;
            float v = tile[tx][pl];
            unsigned short hi = f2bf(v);
            unsigned short lo = f2bf(v - bf2f(hi));
            xthi[(size_t)row * 512 + cb + tx] = hi;
            xtlo[(size_t)row * 512 + cb + tx] = lo;
        }
    }
}

// ---------------------------------------------------------------------------
// P2: wr [oc][c][tap] -> W'[oc][k= tap*512+c] bf16 hi/lo (A-frag layout).
// ---------------------------------------------------------------------------
__global__ __launch_bounds__(256) void p2_w(const float* __restrict__ wr,
                                            unsigned short* __restrict__ whi,
                                            unsigned short* __restrict__ wlo)
{
    int e = blockIdx.x * 256 + threadIdx.x;  // 512*4608
    if (e >= 512 * 4608) return;
    int oc = e / 4608, k = e - oc * 4608;
    int tap = k >> 9, c = k & 511;
    float v = wr[(size_t)oc * 4608 + c * 9 + tap];
    unsigned short hi = f2bf(v);
    whi[e] = hi;
    wlo[e] = f2bf(v - bf2f(hi));
}

// ---------------------------------------------------------------------------
// K1m: conv as bf16x3 MFMA GEMM. D[oc][px] = sum_k W'[oc][k] * X[px][k].
// Wave = 32oc x 64px (2x4 16x16 tiles, 3 MFMA each). Block = 64oc x 128px.
// K-split 3 (48 of 144 k-chunks each) -> pk[3][512][2560] fp32 partials.
// Frags loaded directly from global (inputs are L2/L3-resident, ~15 MB).
// ---------------------------------------------------------------------------
__global__ __launch_bounds__(256) void k1m(const unsigned short* __restrict__ xthi,
                                           const unsigned short* __restrict__ xtlo,
                                           const unsigned short* __restrict__ whi,
                                           const unsigned short* __restrict__ wlo,
                                           float* __restrict__ pk)
{
    int t = threadIdx.x;
    int lane = t & 63, wave = t >> 6;
    int wo = wave & 1, wp = wave >> 1;
    int pb = blockIdx.x, ob = blockIdx.y, bs = blockIdx.z;
    int quad = lane >> 4, m = lane & 15;
    int ocbase = ob * 64 + wo * 32;
    int pxbase = pb * 128 + wp * 64;

    int prow[4];
#pragma unroll
    for (int sp = 0; sp < 4; ++sp) {
        int opx = pxbase + sp * 16 + m;
        // invalid px -> row 190 (y'=2,x'=62): all 9 tap-neighbors are zero rows
        prow[sp] = (opx < NPX) ? ((opx / 50) + 1) * 64 + (opx % 50) + 1 : 190;
    }
    size_t wrow0 = (size_t)(ocbase + m) * 4608;
    size_t wrow1 = (size_t)(ocbase + 16 + m) * 4608;

    f32x4 acc[2][4];
    f32x4 zf = {0.f, 0.f, 0.f, 0.f};
#pragma unroll
    for (int a = 0; a < 2; ++a)
#pragma unroll
        for (int b = 0; b < 4; ++b) acc[a][b] = zf;

    int i0 = bs * 48;
    for (int i = i0; i < i0 + 48; ++i) {
        int tap = i >> 4;                 // 0..8
        int c0 = (i & 15) << 5;           // 0..480
        int kq = c0 + quad * 8;
        int dy = tap / 3 - 1, dx = tap - (tap / 3) * 3 - 1;
        int tapoff = dy * 64 + dx;
        int kw = tap * 512 + kq;

        bf16x8 ah0 = *(const bf16x8*)(whi + wrow0 + kw);
        bf16x8 ah1 = *(const bf16x8*)(whi + wrow1 + kw);
        bf16x8 al0 = *(const bf16x8*)(wlo + wrow0 + kw);
        bf16x8 al1 = *(const bf16x8*)(wlo + wrow1 + kw);
        bf16x8 bh[4], bl[4];
#pragma unroll
        for (int sp = 0; sp < 4; ++sp) {
            size_t off = (size_t)(prow[sp] + tapoff) * 512 + kq;
            bh[sp] = *(const bf16x8*)(xthi + off);
            bl[sp] = *(const bf16x8*)(xtlo + off);
        }
#pragma unroll
        for (int sp = 0; sp < 4; ++sp) {
            acc[0][sp] = __builtin_amdgcn_mfma_f32_16x16x32_bf16(al0, bh[sp], acc[0][sp], 0, 0, 0);
            acc[0][sp] = __builtin_amdgcn_mfma_f32_16x16x32_bf16(ah0, bl[sp], acc[0][sp], 0, 0, 0);
            acc[0][sp] = __builtin_amdgcn_mfma_f32_16x16x32_bf16(ah0, bh[sp], acc[0][sp], 0, 0, 0);
            acc[1][sp] = __builtin_amdgcn_mfma_f32_16x16x32_bf16(al1, bh[sp], acc[1][sp], 0, 0, 0);
            acc[1][sp] = __builtin_amdgcn_mfma_f32_16x16x32_bf16(ah1, bl[sp], acc[1][sp], 0, 0, 0);
            acc[1][sp] = __builtin_amdgcn_mfma_f32_16x16x32_bf16(ah1, bh[sp], acc[1][sp], 0, 0, 0);
        }
    }
    // C/D layout: col(n=px) = lane&15, row(m=oc) = quad*4 + reg
#pragma unroll
    for (int so = 0; so < 2; ++so)
#pragma unroll
        for (int sp = 0; sp < 4; ++sp)
#pragma unroll
            for (int r = 0; r < 4; ++r) {
                int oc = ocbase + so * 16 + quad * 4 + r;
                int px = pxbase + sp * 16 + m;
                pk[((size_t)bs * 512 + oc) * 2560 + px] = acc[so][sp][r];
            }
}

// ---------------------------------------------------------------------------
// K1r: reduce 3 K-split partials + bias + ReLU -> rpn[c][px].
// ---------------------------------------------------------------------------
__global__ __launch_bounds__(256) void k1r(const float* __restrict__ pk,
                                           const float* __restrict__ br,
                                           float* __restrict__ rpn)
{
    int e = blockIdx.x * 256 + threadIdx.x;   // 512*2500
    if (e >= 512 * NPX) return;
    int oc = e / NPX, px = e - oc * NPX;
    size_t base = (size_t)oc * 2560 + px;
    float v = pk[base] + pk[(size_t)512 * 2560 + base] + pk[(size_t)2 * 512 * 2560 + base]
            + br[oc];
    rpn[e] = v > 0.f ? v : 0.f;
}

// ---------------------------------------------------------------------------
// K2a: 1x1 heads partial GEMM, 8 deterministic c-chunks.
// ---------------------------------------------------------------------------
__global__ __launch_bounds__(256) void k2a_heads(const float* __restrict__ rpn,
                                                 const float* __restrict__ wcls,
                                                 const float* __restrict__ wreg,
                                                 float* __restrict__ part)
{
    __shared__ float Wl[45 * 64];
    int t  = threadIdx.x;
    int pb = blockIdx.x;
    int s  = blockIdx.y;
    int cb = s * 64;
    for (int e = t; e < 45 * 64; e += 256) {
        int u = e >> 6, c = e & 63;
        Wl[e] = (u < 9) ? wcls[u * 512 + cb + c] : wreg[(u - 9) * 512 + cb + c];
    }
    __syncthreads();
    int pxl = t & 63;
    int ug  = t >> 6;
    int px  = pb * 64 + pxl;
    int ubase = ug * 12;
    int ulim  = (ubase + 12 <= 45) ? 12 : (45 - ubase);
    float acc[12];
#pragma unroll
    for (int j = 0; j < 12; ++j) acc[j] = 0.f;
    bool ok = px < NPX;
    for (int c = 0; c < 64; ++c) {
        float v = ok ? rpn[(size_t)(cb + c) * NPX + px] : 0.f;
#pragma unroll
        for (int j = 0; j < 12; ++j)
            if (j < ulim) acc[j] = fmaf(v, Wl[(ubase + j) * 64 + c], acc[j]);
    }
    if (ok) {
        for (int j = 0; j < ulim; ++j)
            part[((size_t)s * 45 + ubase + j) * NPX + px] = acc[j];
    }
}

// ---------------------------------------------------------------------------
// K2b: reduce partials + bias, sigmoid, decode, clip, validity, sort key.
// ---------------------------------------------------------------------------
__global__ __launch_bounds__(256) void k2b_decode(const float* __restrict__ part,
                                                  const float* __restrict__ bcls,
                                                  const float* __restrict__ breg,
                                                  AnchorBase ab,
                                                  float* __restrict__ score,
                                                  float* __restrict__ bx1, float* __restrict__ by1,
                                                  float* __restrict__ bx2, float* __restrict__ by2,
                                                  u32* __restrict__ valid,
                                                  u64* __restrict__ key)
{
    int id = blockIdx.x * 256 + threadIdx.x;
    if (id >= NANCH) return;
    int k  = id / NPX;
    int px = id - k * NPX;

    float z  = bcls[k];
    float d0 = breg[k * 4 + 0], d1 = breg[k * 4 + 1];
    float d2 = breg[k * 4 + 2], d3 = breg[k * 4 + 3];
#pragma unroll
    for (int s = 0; s < 8; ++s) {
        const float* p = part + (size_t)s * 45 * NPX;
        z  += p[(size_t)k * NPX + px];
        d0 += p[(size_t)(9 + k * 4 + 0) * NPX + px];
        d1 += p[(size_t)(9 + k * 4 + 1) * NPX + px];
        d2 += p[(size_t)(9 + k * 4 + 2) * NPX + px];
        d3 += p[(size_t)(9 + k * 4 + 3) * NPX + px];
    }
    float sc = 1.f / (1.f + expf(-z));

    int yy = px / 50, xx = px - (px / 50) * 50;
    float fx = (float)xx, fy = (float)yy;
    float ax1 = fx + ab.b[k * 4 + 0], ay1 = fy + ab.b[k * 4 + 1];
    float ax2 = fx + ab.b[k * 4 + 2], ay2 = fy + ab.b[k * 4 + 3];
    float aw = ax2 - ax1, ah = ay2 - ay1;
    float cx = ax1 + 0.5f * aw, cy = ay1 + 0.5f * ah;
    float pcx = d0 * aw + cx, pcy = d1 * ah + cy;
    float pw = expf(d2) * aw, ph = expf(d3) * ah;
    float x1 = pcx - 0.5f * pw, y1 = pcy - 0.5f * ph;
    float x2 = pcx + 0.5f * pw, y2 = pcy + 0.5f * ph;
    x1 = fminf(fmaxf(x1, 0.f), 800.f);
    y1 = fminf(fmaxf(y1, 0.f), 800.f);
    x2 = fminf(fmaxf(x2, 0.f), 800.f);
    y2 = fminf(fmaxf(y2, 0.f), 800.f);
    u32 v = ((x2 - x1) >= 16.f) && ((y2 - y1) >= 16.f);

    int f = px * 9 + k;
    score[f] = sc;
    bx1[f] = x1; by1[f] = y1; bx2[f] = x2; by2[f] = y2;
    valid[f] = v;
    u32 sb = __float_as_uint(sc);
    key[f] = ((u64)(~sb) << 32) | (u32)f;
}

// ---------------------------------------------------------------------------
// K3a: exact stable ranking by counting.
// ---------------------------------------------------------------------------
__global__ __launch_bounds__(256) void k3a_rank(const u64* __restrict__ key,
                                                u32* __restrict__ rank)
{
    __shared__ u64 sk[4500];
    int t  = threadIdx.x;
    int jb = blockIdx.y;
    for (int e = t; e < 4500; e += 256) sk[e] = key[jb * 4500 + e];
    __syncthreads();
    int i = blockIdx.x * 256 + t;
    if (i >= NANCH) return;
    u64 ki = key[i];
    u32 cnt = 0;
#pragma unroll 8
    for (int j = 0; j < 4500; ++j) cnt += (sk[j] < ki) ? 1u : 0u;
    atomicAdd(&rank[i], cnt);
}

// ---------------------------------------------------------------------------
// K3b: scatter top-10000 into sorted arrays; invalid -> initial removed bit.
// ---------------------------------------------------------------------------
__global__ __launch_bounds__(256) void k3b_gather(const u32* __restrict__ rank,
                                                  const float* __restrict__ score,
                                                  const float* __restrict__ bx1, const float* __restrict__ by1,
                                                  const float* __restrict__ bx2, const float* __restrict__ by2,
                                                  const u32* __restrict__ valid,
                                                  float* __restrict__ sS,
                                                  float* __restrict__ sx1, float* __restrict__ sy1,
                                                  float* __restrict__ sx2, float* __restrict__ sy2,
                                                  float* __restrict__ sA,
                                                  u64* __restrict__ rinit)
{
    int i = blockIdx.x * 256 + threadIdx.x;
    if (i >= NANCH) return;
    u32 r = rank[i];
    if (r >= PRE_TOPK) return;
    float x1 = bx1[i], y1 = by1[i], x2 = bx2[i], y2 = by2[i];
    sS[r] = score[i];
    sx1[r] = x1; sy1[r] = y1; sx2[r] = x2; sy2[r] = y2;
    sA[r] = (x2 - x1) * (y2 - y1);
    if (!valid[i]) atomicOr(&rinit[r >> 6], 1ull << (r & 63));
}

// ---------------------------------------------------------------------------
// K4: pairwise suppression matrix + selfw[i] = rows[i][i>>6].
// ---------------------------------------------------------------------------
__global__ __launch_bounds__(256) void k4_mat(const float* __restrict__ sx1, const float* __restrict__ sy1,
                                              const float* __restrict__ sx2, const float* __restrict__ sy2,
                                              const float* __restrict__ sA,
                                              u64* __restrict__ rows,
                                              u64* __restrict__ selfw)
{
    __shared__ float jx1[1024], jy1[1024], jx2[1024], jy2[1024], ja[1024];
    int t  = threadIdx.x;
    int ib = blockIdx.x;
    int jc = blockIdx.y;
    for (int e = t; e < 1024; e += 256) {
        int j = jc * 1024 + e;
        bool okj = j < PRE_TOPK;
        jx1[e] = okj ? sx1[j] : 0.f;
        jy1[e] = okj ? sy1[j] : 0.f;
        jx2[e] = okj ? sx2[j] : 0.f;
        jy2[e] = okj ? sy2[j] : 0.f;
        ja[e]  = okj ? sA[j]  : 0.f;
    }
    __syncthreads();
    int i = ib * 256 + t;
    if (i >= PRE_TOPK) return;
    u64* rowp = rows + (size_t)i * NWORDS + jc * 16;
    if (jc * 1024 + 1023 <= i) {   // whole chunk has j <= i -> zeros
#pragma unroll
        for (int w = 0; w < 16; ++w) rowp[w] = 0ull;
        int sw_ = i >> 6;
        if (sw_ >= jc * 16 && sw_ < jc * 16 + 16) selfw[i] = 0ull;
        return;
    }
    float x1 = sx1[i], y1 = sy1[i], x2 = sx2[i], y2 = sy2[i], ai = sA[i];
    u64 word = 0;
#pragma unroll 4
    for (int e = 0; e < 1024; ++e) {
        int j = jc * 1024 + e;
        float xx1 = fmaxf(x1, jx1[e]);
        float yy1 = fmaxf(y1, jy1[e]);
        float xx2 = fminf(x2, jx2[e]);
        float yy2 = fminf(y2, jy2[e]);
        float iw = fmaxf(xx2 - xx1, 0.f);
        float ih = fmaxf(yy2 - yy1, 0.f);
        float inter = iw * ih;
        float uni = ai + ja[e] - inter;
        bool sup = (inter > 0.7f * uni) && (j > i) && (j < PRE_TOPK);
        word |= ((u64)sup) << (e & 63);
        if ((e & 63) == 63) {
            rowp[e >> 6] = word;
            if ((jc * 16 + (e >> 6)) == (i >> 6)) selfw[i] = word;
            word = 0;
        }
    }
}

// ---------------------------------------------------------------------------
// K5 v2: word-batched greedy NMS scan.
// Per 64-bit word: resolve intra-word suppression entirely in registers via
// prefetched selfw (no memory on the per-bit path), then OR all kept rows of
// the word in batches of 8 parallel loads. Lane l owns words {l,64+l,128+l}.
// ---------------------------------------------------------------------------
__global__ __launch_bounds__(64) void k5_scan(const u64* __restrict__ rows,
                                              const u64* __restrict__ selfw,
                                              const u64* __restrict__ rinit,
                                              const float* __restrict__ sS,
                                              const float* __restrict__ sx1, const float* __restrict__ sy1,
                                              const float* __restrict__ sx2, const float* __restrict__ sy2,
                                              float* __restrict__ out)
{
    __shared__ int keptList[2000];
    __shared__ int kcnt;
    int l = threadIdx.x;
    u64 r0 = rinit[l];
    u64 r1 = rinit[64 + l];
    u64 r2 = (l < 32) ? rinit[128 + l] : ~0ull;
    u64 swreg = selfw[l];                       // word 0 selfs
    int cnt = 0;
    bool done = false;
    for (int w = 0; w < 157 && !done; ++w) {
        u64 swnext = (w < 156) ? selfw[(size_t)(w + 1) * 64 + l] : 0ull;
        int slot = w >> 6, owner = w & 63;
        u64 val = (slot == 0) ? r0 : (slot == 1) ? r1 : r2;
        u64 rw = __shfl(val, owner, 64);
        u64 wmask = (w == 156) ? 0xFFFFull : ~0ull;
        u64 av = (~rw) & wmask;
        // phase A: intra-word resolution, registers only
        u64 km = 0;
        while (av) {
            int b = __ffsll((unsigned long long)av) - 1;
            u64 sw = __shfl(swreg, b, 64);
            km |= 1ull << b;
            av &= ~(1ull << b);
            av &= ~sw;
        }
        // phase B: OR kept rows into removed bitmap, 8 rows per batch
        u64 kk = km;
        while (kk) {
            int bsx[8];
            int nb = 0;
            while (kk && nb < 8) {
                int b = __ffsll((unsigned long long)kk) - 1;
                kk &= kk - 1;
                bsx[nb++] = b;
            }
            u64 a0 = 0, a1 = 0, a2 = 0;
#pragma unroll
            for (int u = 0; u < 8; ++u) {
                if (u < nb) {
                    int i = (w << 6) + bsx[u];
                    if (l == 0 && cnt + u < 2000) keptList[cnt + u] = i;
                    const u64* rp = rows + (size_t)i * NWORDS;
                    a0 |= rp[l];
                    a1 |= rp[64 + l];
                    if (l < 32) a2 |= rp[128 + l];
                }
            }
            r0 |= a0; r1 |= a1; r2 |= a2;
            cnt += nb;
            if (cnt >= 2000) { done = true; break; }
        }
        swreg = swnext;
    }
    if (l == 0) kcnt = (cnt < 2000) ? cnt : 2000;
    __syncthreads();
    int K = kcnt;
    for (int r = l; r < K; r += 64) {
        int j = keptList[r];
        out[r * 4 + 0] = sx1[j];
        out[r * 4 + 1] = sy1[j];
        out[r * 4 + 2] = sx2[j];
        out[r * 4 + 3] = sy2[j];
        out[8000 + r]  = sS[j];
    }
}

// ---------------------------------------------------------------------------
extern "C" void kernel_launch(void* const* d_in, const int* in_sizes, int n_in,
                              void* d_out, int out_size, void* d_ws, size_t ws_size,
                              hipStream_t stream)
{
    (void)in_sizes; (void)n_in; (void)out_size; (void)ws_size;
    const float* feat = (const float*)d_in[1];
    const float* wrpn = (const float*)d_in[3];
    const float* brpn = (const float*)d_in[4];
    const float* wcls = (const float*)d_in[5];
    const float* bcls = (const float*)d_in[6];
    const float* wreg = (const float*)d_in[7];
    const float* breg = (const float*)d_in[8];
    float* out = (float*)d_out;

    char* ws = (char*)d_ws;
    // Live ranges (sequential stream):
    //   Wphi  [P2 .. k1m)          aliases rpn (written first at k1r)
    //   pk    [k1m .. k1r)         aliases part/small/rows (written after k1r)
    //   Xt    [memset .. k1m)      partially aliased by rows/selfw (written at k4)
    float* rpn   = (float*)(ws + 0);                       //  5,120,000
    unsigned short* Wphi = (unsigned short*)(ws + 0);      //  4,718,592 (in rpn)
    float* pk    = (float*)(ws + 5120000);                 // 15,728,640
    float* part  = (float*)(ws + 5120000);                 //  3,600,000 (in pk)
    float* score = (float*)(ws + 8720000);
    float* bx1   = (float*)(ws + 8810000);
    float* by1   = (float*)(ws + 8900000);
    float* bx2   = (float*)(ws + 8990000);
    float* by2   = (float*)(ws + 9080000);
    u32*   valid = (u32*)  (ws + 9170000);
    u64*   key   = (u64*)  (ws + 9260000);
    u32*   rank  = (u32*)  (ws + 9440000);
    float* sS    = (float*)(ws + 9530000);
    float* sx1   = (float*)(ws + 9570000);
    float* sy1   = (float*)(ws + 9610000);
    float* sx2   = (float*)(ws + 9650000);
    float* sy2   = (float*)(ws + 9690000);
    float* sA    = (float*)(ws + 9730000);
    u64*   rinit = (u64*)  (ws + 9770000);                 //  1,280
    u64*   rows  = (u64*)  (ws + 9771280);                 // 12,800,000
    unsigned short* Xthi = (unsigned short*)(ws + 20848640); // 3,407,872
    u64*   selfwp= (u64*)  (ws + 22571280);                //  81,920 (in Xthi, dead)
    unsigned short* Xtlo = (unsigned short*)(ws + 24256512); // 3,407,872
    unsigned short* Wplo = (unsigned short*)(ws + 27664384); // 4,718,592
    // peak concurrent footprint: 32,382,976 bytes

    AnchorBase ab;
    {
        const float scales[3] = {128.f, 256.f, 512.f};
        const float aspect[3] = {0.5f, 1.f, 2.f};
        for (int ai = 0; ai < 3; ++ai) {
            float hr = sqrtf(aspect[ai]);
            float wratio = 1.0f / hr;
            for (int si = 0; si < 3; ++si) {
                float wsz = wratio * scales[si];
                float hsz = hr * scales[si];
                int a = ai * 3 + si;
                ab.b[a * 4 + 0] = rintf(-wsz / 2.0f);
                ab.b[a * 4 + 1] = rintf(-hsz / 2.0f);
                ab.b[a * 4 + 2] = rintf( wsz / 2.0f);
                ab.b[a * 4 + 3] = rintf( hsz / 2.0f);
            }
        }
    }

    // conv: prep + MFMA GEMM + reduce
    hipMemsetAsync(ws + 20848640, 0, 6815744, stream);     // Xthi+Xtlo zero pad
    p1_xt <<<dim3(40, 8), 256, 0, stream>>>(feat, Xthi, Xtlo);
    p2_w  <<<9216, 256, 0, stream>>>(wrpn, Wphi, Wplo);
    k1m   <<<dim3(20, 8, 3), 256, 0, stream>>>(Xthi, Xtlo, Wphi, Wplo, pk);
    k1r   <<<5000, 256, 0, stream>>>(pk, brpn, rpn);

    // memsets AFTER k1r (regions alias pk which is now dead)
    hipMemsetAsync(rank, 0, NANCH * sizeof(u32), stream);
    hipMemsetAsync(rinit, 0, NWORDS * sizeof(u64), stream);
    hipMemsetAsync(out, 0, 10000 * sizeof(float), stream);

    k2a_heads<<<dim3(40, 8), 256, 0, stream>>>(rpn, wcls, wreg, part);
    k2b_decode<<<88, 256, 0, stream>>>(part, bcls, breg, ab, score, bx1, by1, bx2, by2, valid, key);
    k3a_rank <<<dim3(88, 5), 256, 0, stream>>>(key, rank);
    k3b_gather<<<88, 256, 0, stream>>>(rank, score, bx1, by1, bx2, by2, valid,
                                       sS, sx1, sy1, sx2, sy2, sA, rinit);
    k4_mat   <<<dim3(40, 10), 256, 0, stream>>>(sx1, sy1, sx2, sy2, sA, rows, selfwp);
    k5_scan  <<<1, 64, 0, stream>>>(rows, selfwp, rinit, sS, sx1, sy1, sx2, sy2, out);
}